// Round 14
// baseline (66.533 us; speedup 1.0000x reference)
//
#include <hip/hip_runtime.h>
#include <math.h>

#define NNODE 32768   // B*N
constexpr float SCALE = 0.08838834764831845f; // 1/sqrt(128)

typedef unsigned short u16;
typedef __bf16 bf16x8 __attribute__((ext_vector_type(8)));
typedef __bf16 bf16x2 __attribute__((ext_vector_type(2)));
typedef float f32x4 __attribute__((ext_vector_type(4)));

__device__ __forceinline__ u16 f2bf(float f) {
    unsigned u = __float_as_uint(f);
    u += 0x7fff + ((u >> 16) & 1);       // RNE
    return (u16)(u >> 16);
}
__device__ __forceinline__ unsigned pack2bf(float lo, float hi) {
    return (unsigned)f2bf(lo) | ((unsigned)f2bf(hi) << 16);
}
__device__ __forceinline__ void unpack8(uint4 u, float* f) {
    f[0] = __uint_as_float(u.x << 16);  f[1] = __uint_as_float(u.x & 0xffff0000u);
    f[2] = __uint_as_float(u.y << 16);  f[3] = __uint_as_float(u.y & 0xffff0000u);
    f[4] = __uint_as_float(u.z << 16);  f[5] = __uint_as_float(u.z & 0xffff0000u);
    f[6] = __uint_as_float(u.w << 16);  f[7] = __uint_as_float(u.w & 0xffff0000u);
}
// packed bf16 pair dot: c += a0*b0 + a1*b1 (v_dot2_f32_bf16 when available)
__device__ __forceinline__ float dot2bf(unsigned a, unsigned b, float c) {
#if __has_builtin(__builtin_amdgcn_fdot2_f32_bf16)
    union { unsigned u; bf16x2 v; } ua, ub;
    ua.u = a; ub.u = b;
    return __builtin_amdgcn_fdot2_f32_bf16(ua.v, ub.v, c, false);
#else
    float al = __uint_as_float(a << 16), ah = __uint_as_float(a & 0xffff0000u);
    float bl = __uint_as_float(b << 16), bh = __uint_as_float(b & 0xffff0000u);
    return fmaf(ah, bh, fmaf(al, bl, c));
#endif
}
__device__ __forceinline__ float dot8bf(uint4 a, uint4 b, float c) {
    c = dot2bf(a.x, b.x, c);
    c = dot2bf(a.y, b.y, c);
    c = dot2bf(a.z, b.z, c);
    c = dot2bf(a.w, b.w, c);
    return c;
}

// async global->LDS, 16B per lane; LDS dest must be wave-uniform base
__device__ __forceinline__ void gl_lds16(const void* g, void* l) {
    __builtin_amdgcn_global_load_lds(
        (const __attribute__((address_space(1))) unsigned int*)(uintptr_t)g,
        (__attribute__((address_space(3))) unsigned int*)(unsigned int)(uintptr_t)l,
        16, 0, 0);
}

// ---------------- weight prep stage A: four 128^3 MFMA matmuls ---------
// task (dir,kind): kind 0: Af=Wq@wq^T  1: Bmf=Wk@wk^T  2: Wtf=Wv@wv^T
//                  kind 3: RTf = LW_dir @ ow^T  (LW[g][e]=lin_w[g][dir*128+e])
// primitive: C[i][j] = sum_k A[i][k]*BT[j][k]; outputs f32 [i][j].
__global__ __launch_bounds__(256) void wprepA(
    const float* __restrict__ ipw_in, const float* __restrict__ ipw_out,
    const float* __restrict__ Wq_in, const float* __restrict__ Wk_in,
    const float* __restrict__ Wv_in,
    const float* __restrict__ Wq_out, const float* __restrict__ Wk_out,
    const float* __restrict__ Wv_out,
    const float* __restrict__ ow_in, const float* __restrict__ ow_out,
    const float* __restrict__ lin_w,
    float* __restrict__ Af, float* __restrict__ Bmf,
    float* __restrict__ Wtf, float* __restrict__ RTf)
{
    __shared__ __align__(16) u16 As[128 * 128];
    __shared__ __align__(16) u16 Bs[128 * 128];
    const int tid = threadIdx.x, lane = tid & 63, wid = tid >> 6;
    const int l15 = lane & 15, l4 = lane >> 4;
    const int task = blockIdx.x, dir = task & 1, kind = task >> 1;

    const float* ipw = dir ? ipw_out : ipw_in;
    const float* Ag; int lda; const float* Bg; float* outp;
    if (kind == 0)      { Ag = dir ? Wq_out : Wq_in; lda = 128; Bg = ipw;          outp = Af;  }
    else if (kind == 1) { Ag = dir ? Wk_out : Wk_in; lda = 128; Bg = ipw + 16384;  outp = Bmf; }
    else if (kind == 2) { Ag = dir ? Wv_out : Wv_in; lda = 128; Bg = ipw + 32768;  outp = Wtf; }
    else                { Ag = lin_w + dir * 128;    lda = 256; Bg = dir ? ow_out : ow_in; outp = RTf; }
    outp += dir * 16384;

    // stage A (f32 -> bf16, swizzled)
    #pragma unroll
    for (int i = 0; i < 8; ++i) {
        int c = i * 256 + tid, r = c >> 4, cb = c & 15;
        const float* src = &Ag[(size_t)r * lda + cb * 8];
        float4 f0 = *(const float4*)src, f1 = *(const float4*)(src + 4);
        uint4 pk;
        pk.x = pack2bf(f0.x, f0.y); pk.y = pack2bf(f0.z, f0.w);
        pk.z = pack2bf(f1.x, f1.y); pk.w = pack2bf(f1.z, f1.w);
        *(uint4*)&As[r * 128 + ((cb ^ (r & 7)) * 8)] = pk;
    }
    // stage B (natural for kind<3; transposed BT[f][e]=ow[e][f] for kind 3)
    if (kind < 3) {
        #pragma unroll
        for (int i = 0; i < 8; ++i) {
            int c = i * 256 + tid, r = c >> 4, cb = c & 15;
            const float* src = &Bg[(size_t)r * 128 + cb * 8];
            float4 f0 = *(const float4*)src, f1 = *(const float4*)(src + 4);
            uint4 pk;
            pk.x = pack2bf(f0.x, f0.y); pk.y = pack2bf(f0.z, f0.w);
            pk.z = pack2bf(f1.x, f1.y); pk.w = pack2bf(f1.z, f1.w);
            *(uint4*)&Bs[r * 128 + ((cb ^ (r & 7)) * 8)] = pk;
        }
    } else {
        #pragma unroll
        for (int i = 0; i < 8; ++i) {
            int c = i * 256 + tid, f = c >> 4, cb = c & 15;
            u16 tmp[8];
            #pragma unroll
            for (int q = 0; q < 8; ++q)
                tmp[q] = f2bf(Bg[(size_t)(cb * 8 + q) * 128 + f]);
            *(uint4*)&Bs[f * 128 + ((cb ^ (f & 7)) * 8)] = *(const uint4*)tmp;
        }
    }
    __syncthreads();

    const int wr = wid >> 1, wc = wid & 1;
    f32x4 acc[4][4] = {};
    #pragma unroll
    for (int ks = 0; ks < 4; ++ks) {
        bf16x8 a[4], b[4];
        #pragma unroll
        for (int mr = 0; mr < 4; ++mr) {
            int r = wr * 64 + mr * 16 + l15, kb = ks * 4 + l4;
            a[mr] = *(const bf16x8*)((const char*)As + r * 256 + ((kb ^ (r & 7)) << 4));
        }
        #pragma unroll
        for (int nc = 0; nc < 4; ++nc) {
            int r = wc * 64 + nc * 16 + l15, kb = ks * 4 + l4;
            b[nc] = *(const bf16x8*)((const char*)Bs + r * 256 + ((kb ^ (r & 7)) << 4));
        }
        #pragma unroll
        for (int mr = 0; mr < 4; ++mr)
            #pragma unroll
            for (int nc = 0; nc < 4; ++nc)
                acc[mr][nc] = __builtin_amdgcn_mfma_f32_16x16x32_bf16(
                    a[mr], b[nc], acc[mr][nc], 0, 0, 0);
    }
    #pragma unroll
    for (int nc = 0; nc < 4; ++nc) {
        int col = wc * 64 + nc * 16 + l15;
        #pragma unroll
        for (int mr = 0; mr < 4; ++mr)
            #pragma unroll
            for (int j = 0; j < 4; ++j)
                outp[(size_t)(wr * 64 + mr * 16 + l4 * 4 + j) * 128 + col] = acc[mr][nc][j];
    }
}

// ---------------- weight prep stage B: Bcat/QfT matmuls + biases -------
// task 0/1: Bcat[(dir*128+d)][c] = bf16(SCALE * sum_f Bmf[d][f]*Af[c][f])
// task 2/3: QfT[g][dir*128+c]    = bf16(sum_f RTf[g][f]*Wtf[c][f])
// task 4:   ycat[dir*128+d] = SCALE*Wk_d.(wk^T bq); bfin = lin_b + lin_w.z
__global__ __launch_bounds__(256) void wprepB(
    const float* __restrict__ Af, const float* __restrict__ Bmf,
    const float* __restrict__ Wtf, const float* __restrict__ RTf,
    const float* __restrict__ ipw_in, const float* __restrict__ ipw_out,
    const float* __restrict__ ipb_in, const float* __restrict__ ipb_out,
    const float* __restrict__ ow_in, const float* __restrict__ ow_out,
    const float* __restrict__ ob_in, const float* __restrict__ ob_out,
    const float* __restrict__ Wk_in, const float* __restrict__ Wk_out,
    const float* __restrict__ lin_w, const float* __restrict__ lin_b,
    u16* __restrict__ Bcat, u16* __restrict__ QfT,
    float* __restrict__ ycat, float* __restrict__ bfin)
{
    __shared__ __align__(16) u16 As[128 * 128];
    __shared__ __align__(16) u16 Bs[128 * 128];
    const int tid = threadIdx.x, lane = tid & 63, wid = tid >> 6;
    const int l15 = lane & 15, l4 = lane >> 4;
    const int task = blockIdx.x;

    if (task < 4) {
        const int dir = task & 1;
        const bool isB = (task < 2);
        const float* Ag = (isB ? Bmf : RTf) + dir * 16384;
        const float* Bg = (isB ? Af  : Wtf) + dir * 16384;
        #pragma unroll
        for (int i = 0; i < 8; ++i) {
            int c = i * 256 + tid, r = c >> 4, cb = c & 15;
            const float* srcA = &Ag[(size_t)r * 128 + cb * 8];
            float4 a0 = *(const float4*)srcA, a1 = *(const float4*)(srcA + 4);
            uint4 pa;
            pa.x = pack2bf(a0.x, a0.y); pa.y = pack2bf(a0.z, a0.w);
            pa.z = pack2bf(a1.x, a1.y); pa.w = pack2bf(a1.z, a1.w);
            *(uint4*)&As[r * 128 + ((cb ^ (r & 7)) * 8)] = pa;
            const float* srcB = &Bg[(size_t)r * 128 + cb * 8];
            float4 b0 = *(const float4*)srcB, b1 = *(const float4*)(srcB + 4);
            uint4 pb;
            pb.x = pack2bf(b0.x, b0.y); pb.y = pack2bf(b0.z, b0.w);
            pb.z = pack2bf(b1.x, b1.y); pb.w = pack2bf(b1.z, b1.w);
            *(uint4*)&Bs[r * 128 + ((cb ^ (r & 7)) * 8)] = pb;
        }
        __syncthreads();

        const int wr = wid >> 1, wc = wid & 1;
        f32x4 acc[4][4] = {};
        #pragma unroll
        for (int ks = 0; ks < 4; ++ks) {
            bf16x8 a[4], b[4];
            #pragma unroll
            for (int mr = 0; mr < 4; ++mr) {
                int r = wr * 64 + mr * 16 + l15, kb = ks * 4 + l4;
                a[mr] = *(const bf16x8*)((const char*)As + r * 256 + ((kb ^ (r & 7)) << 4));
            }
            #pragma unroll
            for (int nc = 0; nc < 4; ++nc) {
                int r = wc * 64 + nc * 16 + l15, kb = ks * 4 + l4;
                b[nc] = *(const bf16x8*)((const char*)Bs + r * 256 + ((kb ^ (r & 7)) << 4));
            }
            #pragma unroll
            for (int mr = 0; mr < 4; ++mr)
                #pragma unroll
                for (int nc = 0; nc < 4; ++nc)
                    acc[mr][nc] = __builtin_amdgcn_mfma_f32_16x16x32_bf16(
                        a[mr], b[nc], acc[mr][nc], 0, 0, 0);
        }
        #pragma unroll
        for (int nc = 0; nc < 4; ++nc) {
            int col = wc * 64 + nc * 16 + l15;
            #pragma unroll
            for (int mr = 0; mr < 4; ++mr)
                #pragma unroll
                for (int j = 0; j < 4; ++j) {
                    int row = wr * 64 + mr * 16 + l4 * 4 + j;
                    float v = acc[mr][nc][j];
                    if (isB)
                        Bcat[(size_t)(dir * 128 + row) * 128 + col] = f2bf(v * SCALE);
                    else
                        QfT[(size_t)row * 256 + dir * 128 + col] = f2bf(v);
                }
        }
    } else {
        // biases: v_dir[e] = sum_f wk[f][e]*bq[f]; z_dir[e] = ow_row_e.bv + ob[e]
        float* sv = (float*)As;          // [0..255]=v, [256..511]=z
        {
            int dir = tid >> 7, e = tid & 127;
            const float* wk = (dir ? ipw_out : ipw_in) + 16384;
            const float* bq = dir ? ipb_out : ipb_in;
            float s = 0.f;
            for (int f = 0; f < 128; ++f) s = fmaf(wk[(size_t)f * 128 + e], bq[f], s);
            sv[tid] = s;
            const float* ow = dir ? ow_out : ow_in;
            const float* bv = (dir ? ipb_out : ipb_in) + 256;
            float u = 0.f;
            #pragma unroll
            for (int f = 0; f < 128; f += 4) {
                float4 o4 = *(const float4*)&ow[(size_t)e * 128 + f];
                float4 b4 = *(const float4*)&bv[f];
                u = fmaf(o4.x, b4.x, u); u = fmaf(o4.y, b4.y, u);
                u = fmaf(o4.z, b4.z, u); u = fmaf(o4.w, b4.w, u);
            }
            sv[256 + tid] = u + (dir ? ob_out : ob_in)[e];
        }
        __syncthreads();
        {   // ycat[t] = SCALE * Wk_dir_row_d . v_dir
            int dir = tid >> 7, d = tid & 127;
            const float* Wk = dir ? Wk_out : Wk_in;
            const float* v = sv + dir * 128;
            float s = 0.f;
            #pragma unroll
            for (int e = 0; e < 128; e += 4) {
                float4 w4 = *(const float4*)&Wk[(size_t)d * 128 + e];
                s = fmaf(w4.x, v[e], s);     s = fmaf(w4.y, v[e + 1], s);
                s = fmaf(w4.z, v[e + 2], s); s = fmaf(w4.w, v[e + 3], s);
            }
            ycat[tid] = s * SCALE;
        }
        if (tid < 128) {   // bfin[g] = lin_b[g] + lin_w_row_g . z
            const float* lw = lin_w + (size_t)tid * 256;
            const float* z = sv + 256;
            float s = lin_b[tid];
            #pragma unroll
            for (int e2 = 0; e2 < 256; e2 += 4) {
                float4 l4v = *(const float4*)&lw[e2];
                s = fmaf(l4v.x, z[e2], s);     s = fmaf(l4v.y, z[e2 + 1], s);
                s = fmaf(l4v.z, z[e2 + 2], s); s = fmaf(l4v.w, z[e2 + 3], s);
            }
            bfin[tid] = s;
        }
    }
}

// ---------------- kernel: Y GEMM, 32-row tiles for occupancy -----------
// Y[32768][256] = bf16(X) @ Bcat^T + ycat ; Xb = bf16(X) written en route.
// Grid 1024, LDS 8KB(A)+32KB(B) = 40KB -> 4 blocks/CU, 16 waves/CU during
// the latency-critical staging (vs 1 block/CU at the 128-row tile).
__global__ __launch_bounds__(256) void gemm_y32(
    const float* __restrict__ X,
    const u16* __restrict__ BT,
    const float* __restrict__ bias,
    u16* __restrict__ C, u16* __restrict__ Xb)
{
    __shared__ __align__(16) u16 As[32 * 128];    //  8 KB
    __shared__ __align__(16) u16 Bs[128 * 128];   // 32 KB
    const int tid  = threadIdx.x;
    const int lane = tid & 63;
    const int wid  = tid >> 6;
    const int bm  = blockIdx.x * 32;
    const int l15 = lane & 15, l4 = lane >> 4;

    // stage A: read f32 X, convert, swizzled ds_write; also write Xb global
    #pragma unroll
    for (int i = 0; i < 2; ++i) {
        int c = i * 256 + tid;          // chunk id 0..511
        int r = c >> 4, cb = c & 15;
        const float* src = &X[(size_t)(bm + r) * 128 + cb * 8];
        float4 f0 = *(const float4*)src;
        float4 f1 = *(const float4*)(src + 4);
        uint4 pk;
        pk.x = pack2bf(f0.x, f0.y); pk.y = pack2bf(f0.z, f0.w);
        pk.z = pack2bf(f1.x, f1.y); pk.w = pack2bf(f1.z, f1.w);
        *(uint4*)&As[r * 128 + ((cb ^ (r & 7)) * 8)] = pk;
        *(uint4*)&Xb[(size_t)(bm + r) * 128 + cb * 8] = pk;
    }

    #pragma unroll
    for (int nt = 0; nt < 2; ++nt) {
        int bn = nt * 128;
        __syncthreads();                 // A ready (nt=0); prior Bs consumers done (nt=1)
        #pragma unroll
        for (int i = 0; i < 8; ++i) {
            int c = i * 256 + tid;
            int r = c >> 4, cb = c & 15;
            gl_lds16(&BT[(size_t)(bn + r) * 128 + 8 * (cb ^ (r & 7))],
                     &Bs[(size_t)(c - lane) * 8]);
        }
        __syncthreads();

        // wave wid: cols bn + wid*32 + nc*16, rows mr*16
        f32x4 acc[2][2] = {};
        #pragma unroll
        for (int ks = 0; ks < 4; ++ks) {
            bf16x8 a[2], bfr[2];
            #pragma unroll
            for (int mr = 0; mr < 2; ++mr) {
                int r = mr * 16 + l15;
                int kb = ks * 4 + l4;
                a[mr] = *(const bf16x8*)((const char*)As + r * 256 + ((kb ^ (r & 7)) << 4));
            }
            #pragma unroll
            for (int nc = 0; nc < 2; ++nc) {
                int r = wid * 32 + nc * 16 + l15;
                int kb = ks * 4 + l4;
                bfr[nc] = *(const bf16x8*)((const char*)Bs + r * 256 + ((kb ^ (r & 7)) << 4));
            }
            #pragma unroll
            for (int mr = 0; mr < 2; ++mr)
                #pragma unroll
                for (int nc = 0; nc < 2; ++nc)
                    acc[mr][nc] = __builtin_amdgcn_mfma_f32_16x16x32_bf16(
                        a[mr], bfr[nc], acc[mr][nc], 0, 0, 0);
        }
        #pragma unroll
        for (int nc = 0; nc < 2; ++nc) {
            int col = bn + wid * 32 + nc * 16 + l15;
            float bv = bias[col];
            #pragma unroll
            for (int mr = 0; mr < 2; ++mr)
                #pragma unroll
                for (int j = 0; j < 4; ++j) {
                    int row = bm + mr * 16 + l4 * 4 + j;
                    C[(size_t)row * 256 + col] = f2bf(acc[mr][nc][j] + bv);
                }
        }
    }
}

// ---------------- fused attention + output GEMM ------------------------
// Per block: 32 nodes, both dirs. P2: 64 attn items in 4 rounds, results
// to swizzled LDS XC[32][256]. P3: out[32][128] = elu(XC @ QfT^T + bfin).
__global__ __launch_bounds__(256) void attn_out(
    const u16* __restrict__ Y, const u16* __restrict__ Xb,
    const int* __restrict__ in_idx, const int* __restrict__ out_idx,
    const int* __restrict__ in_mask, const int* __restrict__ out_mask,
    const u16* __restrict__ QfT, const float* __restrict__ bfin,
    float* __restrict__ Cout)
{
    __shared__ __align__(16) u16 XC[32 * 256];   // 16 KB, XOR-swizzled

    const int tid  = threadIdx.x;
    const int lane = tid & 63;
    const int wid  = tid >> 6;
    const int l15  = lane & 15, l4 = lane >> 4;

    const int bid  = blockIdx.x;
    const int b    = (bid & 7) >> 1;
    const int s    = ((bid >> 3) << 1) + (bid & 1);   // 0..255
    const int node0 = (b << 13) + s * 32;

    // ---- P2: attention, 64 items (node r, dir) in 4 rounds of 16 groups
    {
        const int g = tid >> 4, l = tid & 15;
        #pragma unroll
        for (int round = 0; round < 4; ++round) {
            const int item = round * 16 + g;
            const int r   = item & 31;
            const int dir = item >> 5;
            const int node = node0 + r;
            const int* idx = dir ? out_idx : in_idx;
            const int* msk = dir ? out_mask : in_mask;

            const int4 i0 = *(const int4*)&idx[(size_t)node * 8];
            const int4 i1 = *(const int4*)&idx[(size_t)node * 8 + 4];
            const int4 m0 = *(const int4*)&msk[(size_t)node * 8];
            const int4 m1 = *(const int4*)&msk[(size_t)node * 8 + 4];
            const int ii[8] = { i0.x, i0.y, i0.z, i0.w, i1.x, i1.y, i1.z, i1.w };
            const int mm[8] = { m0.x, m0.y, m0.z, m0.w, m1.x, m1.y, m1.z, m1.w };

            // issue all loads up front: Y row (self) + 9 Xb rows
            uint4 yv = *(const uint4*)&Y[(size_t)node * 256 + dir * 128 + l * 8];
            uint4 xv[9];
            xv[0] = *(const uint4*)&Xb[(size_t)node * 128 + l * 8];
            #pragma unroll
            for (int t2 = 0; t2 < 8; ++t2)
                xv[t2 + 1] = *(const uint4*)&Xb[(size_t)((b << 13) + ii[t2]) * 128 + l * 8];

            // K-pass: packed dot2, scores pre-scaled via Bcat/ycat
            float sc[9];
            #pragma unroll
            for (int t2 = 0; t2 < 9; ++t2)
                sc[t2] = dot8bf(yv, xv[t2], 0.f);

            #pragma unroll
            for (int t2 = 0; t2 < 9; ++t2) {
                float x = sc[t2];
                x += __shfl_xor(x, 1);
                x += __shfl_xor(x, 2);
                x += __shfl_xor(x, 4);
                x += __shfl_xor(x, 8);
                sc[t2] = x;
            }
            #pragma unroll
            for (int t2 = 1; t2 < 9; ++t2)
                sc[t2] = mm[t2 - 1] ? sc[t2] : -1e30f;

            float m = sc[0];
            #pragma unroll
            for (int t2 = 1; t2 < 9; ++t2) m = fmaxf(m, sc[t2]);
            float w[9], wsum = 0.f;
            #pragma unroll
            for (int t2 = 0; t2 < 9; ++t2) { w[t2] = __expf(sc[t2] - m); wsum += w[t2]; }
            const float inv = 1.f / wsum;

            float acc[8] = {};
            #pragma unroll
            for (int t2 = 0; t2 < 9; ++t2) {
                float vf[8];
                unpack8(xv[t2], vf);
                #pragma unroll
                for (int j = 0; j < 8; ++j) acc[j] = fmaf(w[t2], vf[j], acc[j]);
            }
            uint4 o;
            o.x = pack2bf(acc[0] * inv, acc[1] * inv);
            o.y = pack2bf(acc[2] * inv, acc[3] * inv);
            o.z = pack2bf(acc[4] * inv, acc[5] * inv);
            o.w = pack2bf(acc[6] * inv, acc[7] * inv);
            const int chunk = (dir << 4) + l;            // 0..31
            *(uint4*)((char*)XC + r * 512 + ((chunk ^ (r & 7)) << 4)) = o;
        }
    }
    __syncthreads();

    // ---- P3: out = elu(XC @ QfT^T + bfin) -> f32 ----
    {
        f32x4 acc[2][2] = {};
        #pragma unroll
        for (int ks = 0; ks < 8; ++ks) {
            bf16x8 a[2], bb[2];
            #pragma unroll
            for (int mr = 0; mr < 2; ++mr) {
                int r = mr * 16 + l15;
                int kb = ks * 4 + l4;
                a[mr] = *(const bf16x8*)((const char*)XC + r * 512 + ((kb ^ (r & 7)) << 4));
            }
            #pragma unroll
            for (int nc = 0; nc < 2; ++nc) {
                int col = wid * 32 + nc * 16 + l15;
                bb[nc] = *(const bf16x8*)&QfT[(size_t)col * 256 + (ks * 4 + l4) * 8];
            }
            #pragma unroll
            for (int mr = 0; mr < 2; ++mr)
                #pragma unroll
                for (int nc = 0; nc < 2; ++nc)
                    acc[mr][nc] = __builtin_amdgcn_mfma_f32_16x16x32_bf16(
                        a[mr], bb[nc], acc[mr][nc], 0, 0, 0);
        }
        #pragma unroll
        for (int nc = 0; nc < 2; ++nc) {
            int col = wid * 32 + nc * 16 + l15;
            float bv = bfin[col];
            #pragma unroll
            for (int mr = 0; mr < 2; ++mr)
                #pragma unroll
                for (int j = 0; j < 4; ++j) {
                    int row = mr * 16 + l4 * 4 + j;
                    float v = acc[mr][nc][j] + bv;
                    v = v > 0.f ? v : (__expf(v) - 1.f);
                    Cout[(size_t)(node0 + row) * 128 + col] = v;
                }
        }
    }
}

// ---------------- launch ----------------------------------------------
extern "C" void kernel_launch(void* const* d_in, const int* in_sizes, int n_in,
                              void* d_out, int out_size, void* d_ws, size_t ws_size,
                              hipStream_t stream) {
    const float* X        = (const float*)d_in[0];
    const int*   in_idx   = (const int*)d_in[1];
    const int*   out_idx  = (const int*)d_in[2];
    const int*   in_mask  = (const int*)d_in[3];
    const int*   out_mask = (const int*)d_in[4];
    const float* Wq_in  = (const float*)d_in[5];
    const float* Wk_in  = (const float*)d_in[6];
    const float* Wv_in  = (const float*)d_in[7];
    const float* ipw_in = (const float*)d_in[8];
    const float* ipb_in = (const float*)d_in[9];
    const float* ow_in  = (const float*)d_in[10];
    const float* ob_in  = (const float*)d_in[11];
    const float* Wq_out  = (const float*)d_in[12];
    const float* Wk_out  = (const float*)d_in[13];
    const float* Wv_out  = (const float*)d_in[14];
    const float* ipw_out = (const float*)d_in[15];
    const float* ipb_out = (const float*)d_in[16];
    const float* ow_out  = (const float*)d_in[17];
    const float* ob_out  = (const float*)d_in[18];
    const float* lin_w   = (const float*)d_in[19];
    const float* lin_b   = (const float*)d_in[20];

    char* wsb = (char*)d_ws;
    u16*   Xbw  = (u16*)(wsb + 0);                    //  8,388,608 B
    u16*   Yw   = (u16*)(wsb + 8388608);              // 16,777,216 B
    u16*   Bcat = (u16*)(wsb + 25165824);             //     65,536 B
    u16*   QfT  = (u16*)(wsb + 25231360);             //     65,536 B
    float* Af   = (float*)(wsb + 25296896);           //    131,072 B
    float* Bmf  = (float*)(wsb + 25427968);
    float* Wtf  = (float*)(wsb + 25559040);
    float* RTf  = (float*)(wsb + 25690112);
    float* ycat = (float*)(wsb + 25821184);           //      1,024 B
    float* bfin = (float*)(wsb + 25822208);           //        512 B

    wprepA<<<8, 256, 0, stream>>>(
        ipw_in, ipw_out, Wq_in, Wk_in, Wv_in, Wq_out, Wk_out, Wv_out,
        ow_in, ow_out, lin_w, Af, Bmf, Wtf, RTf);

    wprepB<<<5, 256, 0, stream>>>(
        Af, Bmf, Wtf, RTf, ipw_in, ipw_out, ipb_in, ipb_out,
        ow_in, ow_out, ob_in, ob_out, Wk_in, Wk_out, lin_w, lin_b,
        Bcat, QfT, ycat, bfin);

    gemm_y32<<<1024, 256, 0, stream>>>(X, Bcat, ycat, Yw, Xbw);

    attn_out<<<1024, 256, 0, stream>>>(
        Yw, Xbw, in_idx, out_idx, in_mask, out_mask,
        QfT, bfin, (float*)d_out);
}

// Round 16
// 65.215 us; speedup vs baseline: 1.0202x; 1.0202x over previous
//
#include <hip/hip_runtime.h>
#include <math.h>

#define NNODE 32768   // B*N
constexpr float SCALE = 0.08838834764831845f; // 1/sqrt(128)

typedef unsigned short u16;
typedef __bf16 bf16x8 __attribute__((ext_vector_type(8)));
typedef __bf16 bf16x2 __attribute__((ext_vector_type(2)));
typedef float f32x4 __attribute__((ext_vector_type(4)));

__device__ __forceinline__ u16 f2bf(float f) {
    unsigned u = __float_as_uint(f);
    u += 0x7fff + ((u >> 16) & 1);       // RNE
    return (u16)(u >> 16);
}
__device__ __forceinline__ unsigned pack2bf(float lo, float hi) {
    return (unsigned)f2bf(lo) | ((unsigned)f2bf(hi) << 16);
}
__device__ __forceinline__ void unpack8(uint4 u, float* f) {
    f[0] = __uint_as_float(u.x << 16);  f[1] = __uint_as_float(u.x & 0xffff0000u);
    f[2] = __uint_as_float(u.y << 16);  f[3] = __uint_as_float(u.y & 0xffff0000u);
    f[4] = __uint_as_float(u.z << 16);  f[5] = __uint_as_float(u.z & 0xffff0000u);
    f[6] = __uint_as_float(u.w << 16);  f[7] = __uint_as_float(u.w & 0xffff0000u);
}
// packed bf16 pair dot: c += a0*b0 + a1*b1 (v_dot2_f32_bf16 when available)
__device__ __forceinline__ float dot2bf(unsigned a, unsigned b, float c) {
#if __has_builtin(__builtin_amdgcn_fdot2_f32_bf16)
    union { unsigned u; bf16x2 v; } ua, ub;
    ua.u = a; ub.u = b;
    return __builtin_amdgcn_fdot2_f32_bf16(ua.v, ub.v, c, false);
#else
    float al = __uint_as_float(a << 16), ah = __uint_as_float(a & 0xffff0000u);
    float bl = __uint_as_float(b << 16), bh = __uint_as_float(b & 0xffff0000u);
    return fmaf(ah, bh, fmaf(al, bl, c));
#endif
}
__device__ __forceinline__ float dot8bf(uint4 a, uint4 b, float c) {
    c = dot2bf(a.x, b.x, c);
    c = dot2bf(a.y, b.y, c);
    c = dot2bf(a.z, b.z, c);
    c = dot2bf(a.w, b.w, c);
    return c;
}
__device__ __forceinline__ float dot128(const float* __restrict__ a,
                                        const float* __restrict__ b) {
    float s = 0.f;
    #pragma unroll
    for (int c = 0; c < 128; c += 4) {
        float4 x = *(const float4*)&a[c];
        float4 y = *(const float4*)&b[c];
        s = fmaf(x.x, y.x, s); s = fmaf(x.y, y.y, s);
        s = fmaf(x.z, y.z, s); s = fmaf(x.w, y.w, s);
    }
    return s;
}

// async global->LDS, 16B per lane; LDS dest must be wave-uniform base
__device__ __forceinline__ void gl_lds16(const void* g, void* l) {
    __builtin_amdgcn_global_load_lds(
        (const __attribute__((address_space(1))) unsigned int*)(uintptr_t)g,
        (__attribute__((address_space(3))) unsigned int*)(unsigned int)(uintptr_t)l,
        16, 0, 0);
}

// ---------------- weight prep stage 1 ----------------------------------
// Af=Wq@wq^T, Bmf=Wk@wk^T, Wtf=Wv@wv^T ; RT[g][f]=sum_e ow[e][f]*lin_w[g][dir*128+e]
__global__ __launch_bounds__(256) void wprep1(
    const float* __restrict__ ipw_in, const float* __restrict__ ipw_out,
    const float* __restrict__ Wq_in, const float* __restrict__ Wk_in,
    const float* __restrict__ Wv_in,
    const float* __restrict__ Wq_out, const float* __restrict__ Wk_out,
    const float* __restrict__ Wv_out,
    const float* __restrict__ ow_in, const float* __restrict__ ow_out,
    const float* __restrict__ lin_w,
    float* __restrict__ Af, float* __restrict__ Bmf,
    float* __restrict__ Wtf, float* __restrict__ RTf)
{
    int t = blockIdx.x * 256 + threadIdx.x;   // 0..16383
    int i = t >> 7, j = t & 127;
    int task = blockIdx.y, dir = task & 1, kind = task >> 1;
    if (kind < 3) {
        const float* ipw = dir ? ipw_out : ipw_in;
        const float* W; const float* w; float* outp;
        if (kind == 0)      { W = dir ? Wq_out : Wq_in; w = ipw;          outp = Af;  }
        else if (kind == 1) { W = dir ? Wk_out : Wk_in; w = ipw + 16384;  outp = Bmf; }
        else                { W = dir ? Wv_out : Wv_in; w = ipw + 32768;  outp = Wtf; }
        outp[dir * 16384 + i * 128 + j] = dot128(W + i * 128, w + j * 128);
    } else {
        const float* ow = dir ? ow_out : ow_in;
        const float* lw = lin_w + i * 256 + dir * 128;
        float s = 0.f;
        #pragma unroll
        for (int e = 0; e < 128; e += 4) {
            float4 l4 = *(const float4*)&lw[e];
            s = fmaf(ow[e * 128 + j],       l4.x, s);
            s = fmaf(ow[(e + 1) * 128 + j], l4.y, s);
            s = fmaf(ow[(e + 2) * 128 + j], l4.z, s);
            s = fmaf(ow[(e + 3) * 128 + j], l4.w, s);
        }
        RTf[dir * 16384 + i * 128 + j] = s;
    }
}

// ---------------- weight prep stage 2 ----------------------------------
// Bcat[dir*128+d][c] = SCALE * sum_f A[c][f]*Bm[d][f]   (bf16, pre-scaled)
// QfT[g][dir*128+c]  = sum_f Wt[c][f]*RT[g][f]          (bf16)
// ycat[dir*128+d] = SCALE * (Bm_row_d . bq)
// bfin[g] = lin_b[g] + sum_dir(bv.RT_g + ob.lw_g)
__global__ __launch_bounds__(256) void wprep2(
    const float* __restrict__ Af, const float* __restrict__ Bmf,
    const float* __restrict__ Wtf, const float* __restrict__ RTf,
    const float* __restrict__ ipb_in, const float* __restrict__ ipb_out,
    const float* __restrict__ lin_w, const float* __restrict__ lin_b,
    const float* __restrict__ ob_in, const float* __restrict__ ob_out,
    u16* __restrict__ Bcat, u16* __restrict__ QfT,
    float* __restrict__ ycat, float* __restrict__ bfin)
{
    int task = blockIdx.y;
    int t = blockIdx.x * 256 + threadIdx.x;
    if (task < 2) {
        int dir = task, i = t >> 7, j = t & 127;          // i=d, j=c
        float s = dot128(Af + dir * 16384 + j * 128, Bmf + dir * 16384 + i * 128);
        Bcat[(size_t)(dir * 128 + i) * 128 + j] = f2bf(s * SCALE);
    } else if (task < 4) {
        int dir = task - 2, i = t >> 7, j = t & 127;      // i=g, j=c
        float s = dot128(Wtf + dir * 16384 + j * 128, RTf + dir * 16384 + i * 128);
        QfT[(size_t)i * 256 + dir * 128 + j] = f2bf(s);
    } else {
        if (t < 256) {
            int dir = t >> 7, d = t & 127;
            const float* bq = dir ? ipb_out : ipb_in;
            const float* rb = Bmf + dir * 16384 + d * 128;
            float s = 0.f;
            for (int f = 0; f < 128; ++f) s = fmaf(rb[f], bq[f], s);
            ycat[t] = s * SCALE;
        } else if (t < 384) {
            int g = t - 256;
            float s = lin_b[g];
            #pragma unroll
            for (int dir = 0; dir < 2; ++dir) {
                const float* bv = (dir ? ipb_out : ipb_in) + 256;
                const float* rt = RTf + dir * 16384 + g * 128;
                const float* ob = dir ? ob_out : ob_in;
                const float* lw = lin_w + g * 256 + dir * 128;
                for (int c = 0; c < 128; ++c)
                    s += bv[c] * rt[c] + ob[c] * lw[c];
            }
            bfin[g] = s;
        }
    }
}

// ---------------- kernel: Y GEMM (also emits Xb) -----------------------
// Y[32768][256] = bf16(X) @ Bcat^T + ycat ; Xb = bf16(X) written en route
template<int NT>
__global__ __launch_bounds__(256) void gemm_y(
    const float* __restrict__ X,
    const u16* __restrict__ BT,
    const float* __restrict__ bias,
    u16* __restrict__ C, u16* __restrict__ Xb)
{
    __shared__ __align__(16) u16 As[128 * 128];
    __shared__ __align__(16) u16 Bs[128 * 128];
    const int tid  = threadIdx.x;
    const int lane = tid & 63;
    const int wid  = tid >> 6;
    const int bm  = blockIdx.x * 128;
    const int wr = wid >> 1, wc = wid & 1;
    const int l15 = lane & 15, l4 = lane >> 4;

    // stage A: read f32 X, convert, swizzled ds_write; also write Xb global
    #pragma unroll
    for (int i = 0; i < 8; ++i) {
        int c = i * 256 + tid;          // chunk id 0..2047
        int r = c >> 4, cb = c & 15;
        const float* src = &X[(size_t)(bm + r) * 128 + cb * 8];
        float4 f0 = *(const float4*)src;
        float4 f1 = *(const float4*)(src + 4);
        uint4 pk;
        pk.x = pack2bf(f0.x, f0.y); pk.y = pack2bf(f0.z, f0.w);
        pk.z = pack2bf(f1.x, f1.y); pk.w = pack2bf(f1.z, f1.w);
        *(uint4*)&As[r * 128 + ((cb ^ (r & 7)) * 8)] = pk;
        *(uint4*)&Xb[(size_t)(bm + r) * 128 + cb * 8] = pk;
    }
    __syncthreads();
    bf16x8 a[4][4];
    #pragma unroll
    for (int ks = 0; ks < 4; ++ks)
        #pragma unroll
        for (int mr = 0; mr < 4; ++mr) {
            int r = wr * 64 + mr * 16 + l15;
            int kb = ks * 4 + l4;
            a[ks][mr] = *(const bf16x8*)((const char*)As + r * 256 + ((kb ^ (r & 7)) << 4));
        }

    #pragma unroll
    for (int nt = 0; nt < NT; ++nt) {
        int bn = nt * 128;
        __syncthreads();
        #pragma unroll
        for (int i = 0; i < 8; ++i) {
            int c = i * 256 + tid;
            int r = c >> 4, cb = c & 15;
            gl_lds16(&BT[(size_t)(bn + r) * 128 + 8 * (cb ^ (r & 7))],
                     &Bs[(size_t)(c - lane) * 8]);
        }
        __syncthreads();

        f32x4 acc[4][4] = {};
        #pragma unroll
        for (int ks = 0; ks < 4; ++ks) {
            bf16x8 bfr[4];
            #pragma unroll
            for (int nc = 0; nc < 4; ++nc) {
                int r = wc * 64 + nc * 16 + l15;
                int kb = ks * 4 + l4;
                bfr[nc] = *(const bf16x8*)((const char*)Bs + r * 256 + ((kb ^ (r & 7)) << 4));
            }
            #pragma unroll
            for (int mr = 0; mr < 4; ++mr)
                #pragma unroll
                for (int nc = 0; nc < 4; ++nc)
                    acc[mr][nc] = __builtin_amdgcn_mfma_f32_16x16x32_bf16(
                        a[ks][mr], bfr[nc], acc[mr][nc], 0, 0, 0);
        }
        #pragma unroll
        for (int nc = 0; nc < 4; ++nc) {
            int col = bn + wc * 64 + nc * 16 + l15;
            float bv = bias[col];
            #pragma unroll
            for (int mr = 0; mr < 4; ++mr)
                #pragma unroll
                for (int j = 0; j < 4; ++j) {
                    int row = bm + wr * 64 + mr * 16 + l4 * 4 + j;
                    C[(size_t)row * 256 + col] = f2bf(acc[mr][nc][j] + bv);
                }
        }
    }
}

// ---------------- fused attention + output GEMM ------------------------
// Per block: 32 nodes, both dirs. P2: 64 attn items in 4 rounds, results
// to swizzled LDS XC[32][256]. P3: out[32][128] = elu(XC @ QfT^T + bfin).
// bid&7 keys (batch, parity) -> each XCD's gathers stay in one batch's
// 2MB Xb pool (L2-resident).
__global__ __launch_bounds__(256) void attn_out(
    const u16* __restrict__ Y, const u16* __restrict__ Xb,
    const int* __restrict__ in_idx, const int* __restrict__ out_idx,
    const int* __restrict__ in_mask, const int* __restrict__ out_mask,
    const u16* __restrict__ QfT, const float* __restrict__ bfin,
    float* __restrict__ Cout)
{
    __shared__ __align__(16) u16 XC[32 * 256];   // 16 KB, XOR-swizzled

    const int tid  = threadIdx.x;
    const int lane = tid & 63;
    const int wid  = tid >> 6;
    const int l15  = lane & 15, l4 = lane >> 4;

    const int bid  = blockIdx.x;
    const int b    = (bid & 7) >> 1;
    const int s    = ((bid >> 3) << 1) + (bid & 1);   // 0..255
    const int node0 = (b << 13) + s * 32;

    // ---- P2: attention, 64 items (node r, dir) in 4 rounds of 16 groups
    {
        const int g = tid >> 4, l = tid & 15;
        #pragma unroll
        for (int round = 0; round < 4; ++round) {
            const int item = round * 16 + g;
            const int r   = item & 31;
            const int dir = item >> 5;
            const int node = node0 + r;
            const int* idx = dir ? out_idx : in_idx;
            const int* msk = dir ? out_mask : in_mask;

            const int4 i0 = *(const int4*)&idx[(size_t)node * 8];
            const int4 i1 = *(const int4*)&idx[(size_t)node * 8 + 4];
            const int4 m0 = *(const int4*)&msk[(size_t)node * 8];
            const int4 m1 = *(const int4*)&msk[(size_t)node * 8 + 4];
            const int ii[8] = { i0.x, i0.y, i0.z, i0.w, i1.x, i1.y, i1.z, i1.w };
            const int mm[8] = { m0.x, m0.y, m0.z, m0.w, m1.x, m1.y, m1.z, m1.w };

            // issue all loads up front: Y row (self) + 9 Xb rows
            uint4 yv = *(const uint4*)&Y[(size_t)node * 256 + dir * 128 + l * 8];
            uint4 xv[9];
            xv[0] = *(const uint4*)&Xb[(size_t)node * 128 + l * 8];
            #pragma unroll
            for (int t2 = 0; t2 < 8; ++t2)
                xv[t2 + 1] = *(const uint4*)&Xb[(size_t)((b << 13) + ii[t2]) * 128 + l * 8];

            // K-pass: packed dot2, scores pre-scaled via Bcat/ycat
            float sc[9];
            #pragma unroll
            for (int t2 = 0; t2 < 9; ++t2)
                sc[t2] = dot8bf(yv, xv[t2], 0.f);

            #pragma unroll
            for (int t2 = 0; t2 < 9; ++t2) {
                float x = sc[t2];
                x += __shfl_xor(x, 1);
                x += __shfl_xor(x, 2);
                x += __shfl_xor(x, 4);
                x += __shfl_xor(x, 8);
                sc[t2] = x;
            }
            #pragma unroll
            for (int t2 = 1; t2 < 9; ++t2)
                sc[t2] = mm[t2 - 1] ? sc[t2] : -1e30f;

            float m = sc[0];
            #pragma unroll
            for (int t2 = 1; t2 < 9; ++t2) m = fmaxf(m, sc[t2]);
            float w[9], wsum = 0.f;
            #pragma unroll
            for (int t2 = 0; t2 < 9; ++t2) { w[t2] = __expf(sc[t2] - m); wsum += w[t2]; }
            const float inv = 1.f / wsum;

            float acc[8] = {};
            #pragma unroll
            for (int t2 = 0; t2 < 9; ++t2) {
                float vf[8];
                unpack8(xv[t2], vf);
                #pragma unroll
                for (int j = 0; j < 8; ++j) acc[j] = fmaf(w[t2], vf[j], acc[j]);
            }
            uint4 o;
            o.x = pack2bf(acc[0] * inv, acc[1] * inv);
            o.y = pack2bf(acc[2] * inv, acc[3] * inv);
            o.z = pack2bf(acc[4] * inv, acc[5] * inv);
            o.w = pack2bf(acc[6] * inv, acc[7] * inv);
            const int chunk = (dir << 4) + l;            // 0..31
            *(uint4*)((char*)XC + r * 512 + ((chunk ^ (r & 7)) << 4)) = o;
        }
    }
    __syncthreads();

    // ---- P3: out = elu(XC @ QfT^T + bfin) -> f32 ----
    {
        f32x4 acc[2][2] = {};
        #pragma unroll
        for (int ks = 0; ks < 8; ++ks) {
            bf16x8 a[2], bb[2];
            #pragma unroll
            for (int mr = 0; mr < 2; ++mr) {
                int r = mr * 16 + l15;
                int kb = ks * 4 + l4;
                a[mr] = *(const bf16x8*)((const char*)XC + r * 512 + ((kb ^ (r & 7)) << 4));
            }
            #pragma unroll
            for (int nc = 0; nc < 2; ++nc) {
                int col = wid * 32 + nc * 16 + l15;
                bb[nc] = *(const bf16x8*)&QfT[(size_t)col * 256 + (ks * 4 + l4) * 8];
            }
            #pragma unroll
            for (int mr = 0; mr < 2; ++mr)
                #pragma unroll
                for (int nc = 0; nc < 2; ++nc)
                    acc[mr][nc] = __builtin_amdgcn_mfma_f32_16x16x32_bf16(
                        a[mr], bb[nc], acc[mr][nc], 0, 0, 0);
        }
        #pragma unroll
        for (int nc = 0; nc < 2; ++nc) {
            int col = wid * 32 + nc * 16 + l15;
            float bv = bfin[col];
            #pragma unroll
            for (int mr = 0; mr < 2; ++mr)
                #pragma unroll
                for (int j = 0; j < 4; ++j) {
                    int row = mr * 16 + l4 * 4 + j;
                    float v = acc[mr][nc][j] + bv;
                    v = v > 0.f ? v : (__expf(v) - 1.f);
                    Cout[(size_t)(node0 + row) * 128 + col] = v;
                }
        }
    }
}

// ---------------- launch ----------------------------------------------
extern "C" void kernel_launch(void* const* d_in, const int* in_sizes, int n_in,
                              void* d_out, int out_size, void* d_ws, size_t ws_size,
                              hipStream_t stream) {
    const float* X        = (const float*)d_in[0];
    const int*   in_idx   = (const int*)d_in[1];
    const int*   out_idx  = (const int*)d_in[2];
    const int*   in_mask  = (const int*)d_in[3];
    const int*   out_mask = (const int*)d_in[4];
    const float* Wq_in  = (const float*)d_in[5];
    const float* Wk_in  = (const float*)d_in[6];
    const float* Wv_in  = (const float*)d_in[7];
    const float* ipw_in = (const float*)d_in[8];
    const float* ipb_in = (const float*)d_in[9];
    const float* ow_in  = (const float*)d_in[10];
    const float* ob_in  = (const float*)d_in[11];
    const float* Wq_out  = (const float*)d_in[12];
    const float* Wk_out  = (const float*)d_in[13];
    const float* Wv_out  = (const float*)d_in[14];
    const float* ipw_out = (const float*)d_in[15];
    const float* ipb_out = (const float*)d_in[16];
    const float* ow_out  = (const float*)d_in[17];
    const float* ob_out  = (const float*)d_in[18];
    const float* lin_w   = (const float*)d_in[19];
    const float* lin_b   = (const float*)d_in[20];

    char* wsb = (char*)d_ws;
    u16*   Xbw  = (u16*)(wsb + 0);                    //  8,388,608 B
    u16*   Yw   = (u16*)(wsb + 8388608);              // 16,777,216 B
    u16*   Bcat = (u16*)(wsb + 25165824);             //     65,536 B
    u16*   QfT  = (u16*)(wsb + 25231360);             //     65,536 B
    float* Af   = (float*)(wsb + 25296896);           //    131,072 B
    float* Bmf  = (float*)(wsb + 25427968);
    float* Wtf  = (float*)(wsb + 25559040);
    float* RTf  = (float*)(wsb + 25690112);
    float* ycat = (float*)(wsb + 25821184);           //      1,024 B
    float* bfin = (float*)(wsb + 25822208);           //        512 B

    wprep1<<<dim3(64, 8), 256, 0, stream>>>(
        ipw_in, ipw_out, Wq_in, Wk_in, Wv_in, Wq_out, Wk_out, Wv_out,
        ow_in, ow_out, lin_w, Af, Bmf, Wtf, RTf);

    wprep2<<<dim3(64, 5), 256, 0, stream>>>(
        Af, Bmf, Wtf, RTf, ipb_in, ipb_out, lin_w, lin_b, ob_in, ob_out,
        Bcat, QfT, ycat, bfin);

    gemm_y<2><<<dim3(256, 1), 256, 0, stream>>>(X, Bcat, ycat, Yw, Xbw);

    attn_out<<<1024, 256, 0, stream>>>(
        Yw, Xbw, in_idx, out_idx, in_mask, out_mask,
        QfT, bfin, (float*)d_out);
}